// Round 15
// baseline (2023.042 us; speedup 1.0000x reference)
//
#include <hip/hip_runtime.h>
#include <math.h>

// ---------------------------------------------------------------------------
// sLSTM block, round 15: FFN staging via global_load_lds on pre-swizzled bf16
// tile images (ladder step 3). cvt_z applies LN2 ONCE per row (was 16x inline
// in ff1) and writes z-bf16 tile images; cvt_w writes W1/W2 tile images; ff1
// writes g as tile images for ff2. ff1/ff2 K-loops stage with pure gll16 (no
// staging VALU). Scan/proj/post = r14 (unchanged).
// Workspace (floats): r0 32MB (proj -> g16MB+zb8MB) | state 128KB | mu/rs
// 256KB | w1b 8MB | w2b 4MB | hh2 128KB  (~44.6 MB)
// ---------------------------------------------------------------------------

#define D_MODEL 1024
#define NHEAD   8
#define DPH     128
#define DFF     2048
#define BATCH   8
#define SEQ     2048
#define NROWS   (BATCH * SEQ)   // 16384
#define CHUNK_L 256             // scan steps per launch (8 launches)
#define TGRP    16              // scan steps per staged group (unrolled)
#define NGRP    (CHUNK_L / TGRP)
#define ROWCH   4096            // FFN rows per chunk (4 chunks)
#define LN_EPS  1e-5f

typedef __attribute__((ext_vector_type(8))) short short8;
typedef __attribute__((ext_vector_type(4))) short short4v;
typedef __attribute__((ext_vector_type(4))) float f32x4;
typedef __attribute__((ext_vector_type(2))) _Float16 h2f;
typedef __attribute__((ext_vector_type(8))) _Float16 h8f;
union H8U { h8f v; h2f p[4]; };

#if __has_builtin(__builtin_amdgcn_fdot2)
#define DOT2(a, b, c) __builtin_amdgcn_fdot2((a), (b), (c), false)
#else
__device__ __forceinline__ float DOT2(h2f a, h2f b, float c) {
  return c + (float)a.x * (float)b.x + (float)a.y * (float)b.y;
}
#endif

#if __has_builtin(__builtin_amdgcn_rcpf)
#define FRCP(x) __builtin_amdgcn_rcpf(x)
#else
#define FRCP(x) (1.0f / (x))
#endif

__device__ __forceinline__ float qxor1(float v) {
#if __has_builtin(__builtin_amdgcn_update_dpp)
  union { float f; int i; } u; u.f = v;
  u.i = __builtin_amdgcn_update_dpp(u.i, u.i, 0xB1, 0xf, 0xf, true);
  return u.f;
#else
  return __shfl_xor(v, 1, 64);
#endif
}
__device__ __forceinline__ float qxor2(float v) {
#if __has_builtin(__builtin_amdgcn_update_dpp)
  union { float f; int i; } u; u.f = v;
  u.i = __builtin_amdgcn_update_dpp(u.i, u.i, 0x4E, 0xf, 0xf, true);
  return u.f;
#else
  return __shfl_xor(v, 2, 64);
#endif
}

// async global->LDS, 16B per lane; lds_base must be WAVE-UNIFORM (HW adds lane*16)
__device__ __forceinline__ void gll16(const void* src, void* lds_base, int lane) {
#if __has_builtin(__builtin_amdgcn_global_load_lds)
  __builtin_amdgcn_global_load_lds(
      (const __attribute__((address_space(1))) unsigned int*)src,
      (__attribute__((address_space(3))) unsigned int*)lds_base, 16, 0, 0);
#else
  *(float4*)((char*)lds_base + lane * 16) = *(const float4*)src;
#endif
}

__device__ __forceinline__ float gelu_exact(float x) {
  return 0.5f * x * (1.0f + erff(x * 0.70710678118654752440f));
}

__device__ __forceinline__ unsigned short f2bf(float f) {
  union { float f; unsigned int u; } v; v.f = f;
  unsigned int r = v.u + 0x7fffu + ((v.u >> 16) & 1u);
  return (unsigned short)(r >> 16);
}

// tile-image offset for element (r, k) inside a [128][64] bf16 tile
// (XOR-swizzled to match the MFMA fragment ds_read_b128 pattern)
__device__ __forceinline__ int img_off(int r, int k) {
  return r * 64 + ((((k >> 3) & 7) ^ (r & 7)) << 3) + (k & 7);
}

// one sLSTM gate update (division-free); returns raw h
__device__ __forceinline__ float gate_step(float iv, float fv, float zraw, float oraw,
                                           float& c, float& nrm, float& m) {
  const float zv = 1.0f - 2.0f * FRCP(__expf(2.0f * zraw) + 1.0f);
  const float ov = FRCP(1.0f + __expf(-oraw));
  const float lf = fminf(fv, 0.0f) - __logf(1.0f + __expf(-fabsf(fv)));
  const float ft = lf + m;
  const float mn = fmaxf(ft, iv);
  const float is = __expf(iv - mn);
  const float fs = __expf(ft - mn);
  c = fs * c + is * zv;
  nrm = fs * nrm + is;
  m = mn;
  return ov * c * FRCP(nrm);
}

// --------------------- per-row LN stats (mu, rstd) --------------------------
__global__ __launch_bounds__(256) void ln_stats_kernel(
    const float* __restrict__ in, float* __restrict__ mu_out,
    float* __restrict__ rs_out) {
  const int row = blockIdx.x, tid = threadIdx.x;
  const float4 v = ((const float4*)(in + (size_t)row * D_MODEL))[tid];
  float s  = v.x + v.y + v.z + v.w;
  float s2 = v.x*v.x + v.y*v.y + v.z*v.z + v.w*v.w;
  #pragma unroll
  for (int m = 1; m < 64; m <<= 1) { s += __shfl_xor(s, m, 64); s2 += __shfl_xor(s2, m, 64); }
  __shared__ float sa[4], sb[4];
  if ((tid & 63) == 0) { sa[tid >> 6] = s; sb[tid >> 6] = s2; }
  __syncthreads();
  if (tid == 0) {
    const float S  = sa[0] + sa[1] + sa[2] + sa[3];
    const float S2 = sb[0] + sb[1] + sb[2] + sb[3];
    const float mu = S * (1.0f / D_MODEL);
    const float var = S2 * (1.0f / D_MODEL) - mu * mu;
    mu_out[row] = mu;
    rs_out[row] = rsqrtf(var + LN_EPS);
  }
}

// ---- weight convert: [K][N] f32 -> bf16 tile images [(n>>7)*(K/64)+(k>>6)] --
__global__ __launch_bounds__(256) void cvt_w(
    const float* __restrict__ src, short* __restrict__ dst, int K, int N) {
  __shared__ float tile[64][68];
  const int n0 = blockIdx.x * 64;
  const int k0 = blockIdx.y * 64;
  const int tid = threadIdx.x;
  #pragma unroll
  for (int i = 0; i < 16; ++i) {
    const int e = i * 256 + tid;
    const int kk = e >> 6, nn = e & 63;
    tile[kk][nn] = src[(size_t)(k0 + kk) * N + n0 + nn];
  }
  __syncthreads();
  const int ktiles = K >> 6;
  #pragma unroll
  for (int i = 0; i < 2; ++i) {
    const int e = i * 256 + tid;
    const int nn = e >> 3, kc = (e & 7) * 8;     // kc: k within 64-block
    short8 s;
    #pragma unroll
    for (int j = 0; j < 8; ++j) s[j] = (short)f2bf(tile[kc + j][nn]);
    const int n = n0 + nn;
    const size_t base = ((size_t)(n >> 7) * ktiles + (k0 >> 6)) * 8192;
    *(short8*)(dst + base + img_off(n & 127, kc)) = s;
  }
}

// ---- hh_w [128][512] f32 -> packed f16 pairs hh2[k2][512] -------------------
__global__ __launch_bounds__(256) void cvt_hh(
    const float* __restrict__ hhw, h2f* __restrict__ hh2) {
  const int idx = blockIdx.x * 256 + threadIdx.x;
  const int k2 = idx >> 9, j = idx & 511;
  h2f v;
  v.x = (_Float16)hhw[(size_t)(2 * k2) * 512 + j];
  v.y = (_Float16)hhw[(size_t)(2 * k2 + 1) * 512 + j];
  hh2[idx] = v;
}

// --------------------------- head projection GEMM (r14) ---------------------
__global__ __launch_bounds__(256) void proj_gemm(
    const float* __restrict__ x, const float* __restrict__ mu1,
    const float* __restrict__ rs1, const float* __restrict__ ln1w,
    const float* __restrict__ ln1b, const float* __restrict__ ihw,
    const float* __restrict__ ihb, float* __restrict__ proj, int l0) {
  __shared__ __align__(16) float As[64][68];
  __shared__ __align__(16) float Bs[64][128];
  const int h  = blockIdx.z;
  const int qb = blockIdx.y;
  const int n0 = qb * 128;
  const int m0 = blockIdx.x * 64;
  const int tid = threadIdx.x;
  const int tm = (tid >> 5) << 3;
  const int tn = (tid & 31) << 2;
  float acc[8][4] = {};
  const float* Bb = ihw + (size_t)h * DPH * 512;
  for (int k0 = 0; k0 < DPH; k0 += 64) {
    #pragma unroll
    for (int i = 0; i < 4; ++i) {
      int idx = tid + i * 256;
      int r = idx >> 4, kk = (idx & 15) << 2;
      const int rowm = m0 + r;
      const int l = l0 + (rowm >> 3), b = rowm & 7;
      const int grow = b * SEQ + l;
      const float4 v = *(const float4*)(x + (size_t)grow * D_MODEL + h * DPH + k0 + kk);
      const float mu = mu1[grow], rs = rs1[grow];
      const float4 wv = *(const float4*)(ln1w + h * DPH + k0 + kk);
      const float4 bv = *(const float4*)(ln1b + h * DPH + k0 + kk);
      float4 o;
      o.x = (v.x - mu) * rs * wv.x + bv.x;
      o.y = (v.y - mu) * rs * wv.y + bv.y;
      o.z = (v.z - mu) * rs * wv.z + bv.z;
      o.w = (v.w - mu) * rs * wv.w + bv.w;
      *(float4*)&As[r][kk] = o;
    }
    #pragma unroll
    for (int i = 0; i < 8; ++i) {
      int idx = tid + i * 256;
      int kk = idx >> 5, nn = (idx & 31) << 2;
      *(float4*)&Bs[kk][nn] = *(const float4*)(Bb + (size_t)(k0 + kk) * 512 + n0 + nn);
    }
    __syncthreads();
    #pragma unroll 4
    for (int kk = 0; kk < 64; ++kk) {
      float a[8];
      #pragma unroll
      for (int i = 0; i < 8; ++i) a[i] = As[tm + i][kk];
      const float4 bv = *(const float4*)&Bs[kk][tn];
      #pragma unroll
      for (int i = 0; i < 8; ++i) {
        acc[i][0] += a[i] * bv.x; acc[i][1] += a[i] * bv.y;
        acc[i][2] += a[i] * bv.z; acc[i][3] += a[i] * bv.w;
      }
    }
    __syncthreads();
  }
  const float4 bias = *(const float4*)(ihb + h * 512 + n0 + tn);
  const int pos = n0 + ((tn + 8 * qb) & 127);     // bank-rotated, float4-safe
  #pragma unroll
  for (int i = 0; i < 8; ++i) {
    const int rowm = m0 + tm + i;
    float4 o;
    o.x = acc[i][0] + bias.x; o.y = acc[i][1] + bias.y;
    o.z = acc[i][2] + bias.z; o.w = acc[i][3] + bias.w;
    *(float4*)(proj + ((size_t)rowm * NHEAD + h) * 512 + pos) = o;
  }
}

// ------------------------------- sLSTM scan (r14) ---------------------------
__global__ __launch_bounds__(512, 1) void scan_chunk(
    const float* __restrict__ proj, const h2f* __restrict__ hh2,
    float* __restrict__ state, float* __restrict__ hout, int l0) {
  const int bh = blockIdx.x, b = bh >> 3, h = bh & 7;
  const int tid = threadIdx.x;
  const int l = tid & 63, w = tid >> 6;
  const int q = l & 3, p = l >> 2;
  const int ch = 16 * w + p;
  const int pvoff = q * 128 + ((ch + 8 * q) & 127);
  __shared__ __align__(16) _Float16 h16[2][128];
  __shared__ __align__(16) float pbuf[2][TGRP][512];
  __shared__ __align__(16) float hstage[2][TGRP][128];

  h2f w2[4][16];
  #pragma unroll
  for (int j = 0; j < 4; ++j)
    #pragma unroll
    for (int kk = 0; kk < 16; ++kk)
      w2[j][kk] = hh2[(size_t)(16 * q + kk) * 512 + j * 128 + ch];

  float c, nrm, m;
  if (l0 == 0) {
    c = 0.0f; nrm = 0.0f; m = -1e30f;
    if (q == 0) h16[0][ch] = (_Float16)0.0f;
  } else {
    c   = state[bh * 128 + ch];
    nrm = state[8192  + bh * 128 + ch];
    m   = state[16384 + bh * 128 + ch];
    if (q == 0) h16[0][ch] = (_Float16)state[24576 + bh * 128 + ch];
  }

  const float* pbase = proj + (size_t)bh * 512;

  #define STAGE(NB, GR)                                                        \
    {                                                                          \
      _Pragma("unroll")                                                        \
      for (int i = 0; i < 4; ++i) {                                            \
        const int hr = i * 8 + w;                                              \
        const float* src = pbase + (size_t)((GR) * TGRP + (hr >> 1)) * 32768   \
                           + (hr & 1) * 256 + l * 4;                           \
        float* dst = &pbuf[NB][0][0] + hr * 256;                               \
        gll16(src, dst, l);                                                    \
      }                                                                        \
    }

  STAGE(0, 0)
  asm volatile("s_waitcnt vmcnt(0)" ::: "memory");
  __syncthreads();

  float hv = 0.0f;
  for (int grp = 0; grp < NGRP; ++grp) {
    const int gb = grp & 1;
    if (grp + 1 < NGRP) STAGE(gb ^ 1, grp + 1)
    #pragma unroll
    for (int tl = 0; tl < TGRP; ++tl) {
      const int cur = tl & 1;
      float pa0 = 0.0f, pa1 = 0.0f, pa2 = 0.0f, pa3 = 0.0f;
      {
        const h8f* hp = (const h8f*)&h16[cur][q * 32];
        #pragma unroll
        for (int i = 0; i < 4; ++i) {
          H8U u; u.v = hp[i];
          #pragma unroll
          for (int e = 0; e < 4; ++e) {
            const int kk = i * 4 + e;
            pa0 = DOT2(u.p[e], w2[0][kk], pa0);
            pa1 = DOT2(u.p[e], w2[1][kk], pa1);
            pa2 = DOT2(u.p[e], w2[2][kk], pa2);
            pa3 = DOT2(u.p[e], w2[3][kk], pa3);
          }
        }
      }
      const float pv = pbuf[gb][tl][pvoff];
      pa0 += (q == 0) ? pv : 0.0f;
      pa1 += (q == 1) ? pv : 0.0f;
      pa2 += (q == 2) ? pv : 0.0f;
      pa3 += (q == 3) ? pv : 0.0f;
      pa0 += qxor1(pa0); pa1 += qxor1(pa1); pa2 += qxor1(pa2); pa3 += qxor1(pa3);
      pa0 += qxor2(pa0); pa1 += qxor2(pa1); pa2 += qxor2(pa2); pa3 += qxor2(pa3);
      hv = gate_step(pa0, pa1, pa2, pa3, c, nrm, m);
      if (q == 0) {
        h16[cur ^ 1][ch] = (_Float16)hv;
        hstage[gb][tl][ch] = hv;
      }
      __syncthreads();
    }
    {
      const int s = tid >> 5, c8 = (tid & 31) << 2;
      const float4 v0 = *(const float4*)&hstage[gb][s][c8];
      *(float4*)(hout + ((size_t)(b * SEQ + l0 + grp * TGRP + s)) * D_MODEL
                 + h * DPH + c8) = v0;
    }
  }

  if (q == 0) {
    state[bh * 128 + ch]          = c;
    state[8192  + bh * 128 + ch]  = nrm;
    state[16384 + bh * 128 + ch]  = m;
    state[24576 + bh * 128 + ch]  = hv;
  }
  #undef STAGE
}

// ---------- post: y = headLN(h) + x in place on d_out ; LN2 row stats -------
__global__ __launch_bounds__(256) void post_kernel(
    float* __restrict__ yio, const float* __restrict__ x,
    const float* __restrict__ hnw, const float* __restrict__ hnb,
    float* __restrict__ mu2, float* __restrict__ rs2) {
  const int row = blockIdx.x, tid = threadIdx.x;
  const float4 hv = ((const float4*)(yio + (size_t)row * D_MODEL))[tid];
  float s  = hv.x + hv.y + hv.z + hv.w;
  float s2 = hv.x*hv.x + hv.y*hv.y + hv.z*hv.z + hv.w*hv.w;
  #pragma unroll
  for (int mm = 1; mm < 32; mm <<= 1) {
    s  += __shfl_xor(s,  mm, 32);
    s2 += __shfl_xor(s2, mm, 32);
  }
  const float mu = s * (1.0f / DPH);
  const float var = s2 * (1.0f / DPH) - mu * mu;
  const float rstd = rsqrtf(var + LN_EPS);
  const int dq = tid & 31;
  const float4 w4 = ((const float4*)hnw)[dq];
  const float4 b4 = ((const float4*)hnb)[dq];
  const float4 xv = ((const float4*)(x + (size_t)row * D_MODEL))[tid];
  float4 yv;
  yv.x = (hv.x - mu) * rstd * w4.x + b4.x + xv.x;
  yv.y = (hv.y - mu) * rstd * w4.y + b4.y + xv.y;
  yv.z = (hv.z - mu) * rstd * w4.z + b4.z + xv.z;
  yv.w = (hv.w - mu) * rstd * w4.w + b4.w + xv.w;
  ((float4*)(yio + (size_t)row * D_MODEL))[tid] = yv;
  float t1 = yv.x + yv.y + yv.z + yv.w;
  float t2 = yv.x*yv.x + yv.y*yv.y + yv.z*yv.z + yv.w*yv.w;
  #pragma unroll
  for (int mm = 1; mm < 64; mm <<= 1) {
    t1 += __shfl_xor(t1, mm, 64);
    t2 += __shfl_xor(t2, mm, 64);
  }
  __shared__ float sa[4], sb[4];
  if ((tid & 63) == 0) { sa[tid >> 6] = t1; sb[tid >> 6] = t2; }
  __syncthreads();
  if (tid == 0) {
    const float S  = sa[0] + sa[1] + sa[2] + sa[3];
    const float S2 = sb[0] + sb[1] + sb[2] + sb[3];
    const float m2 = S * (1.0f / D_MODEL);
    const float v2 = S2 * (1.0f / D_MODEL) - m2 * m2;
    mu2[row] = m2;
    rs2[row] = rsqrtf(v2 + LN_EPS);
  }
}

// ------ cvt_z: z = LN2(y) as bf16 tile images (per ROWCH chunk) -------------
// image index: [(lrow>>7)*16 + (k>>6)] ; inside: img_off(lrow&127, k&63)
__global__ __launch_bounds__(256) void cvt_z(
    const float* __restrict__ y, const float* __restrict__ mu2,
    const float* __restrict__ rs2, const float* __restrict__ ln2w,
    const float* __restrict__ ln2b, short* __restrict__ zb, int row0) {
  const int lrow = blockIdx.x, tid = threadIdx.x;
  const int grow = row0 + lrow;
  const float4 v = ((const float4*)(y + (size_t)grow * D_MODEL))[tid];
  const float mu = mu2[grow], rs = rs2[grow];
  const float4 w4 = ((const float4*)ln2w)[tid];
  const float4 b4 = ((const float4*)ln2b)[tid];
  short4v s;
  s[0] = (short)f2bf((v.x - mu) * rs * w4.x + b4.x);
  s[1] = (short)f2bf((v.y - mu) * rs * w4.y + b4.y);
  s[2] = (short)f2bf((v.z - mu) * rs * w4.z + b4.z);
  s[3] = (short)f2bf((v.w - mu) * rs * w4.w + b4.w);
  const int k = tid * 4;
  const size_t base = ((size_t)(lrow >> 7) * 16 + (k >> 6)) * 8192;
  *(short4v*)(zb + base + img_off(lrow & 127, k & 63)) = s;
}

// ------------------------------ FF1 (bf16 MFMA, gll16) ----------------------
// A = zb tile images (chunk-local), B = w1b tile images; g out as tile images.
__global__ __launch_bounds__(256) void ff1_gemm(
    const short* __restrict__ zb, const short* __restrict__ w1b,
    const float* __restrict__ b1, short* __restrict__ g) {
  __shared__ short As[128 * 64];
  __shared__ short Bs1[128 * 64];
  __shared__ short Bs2[128 * 64];
  const int tid = threadIdx.x;
  const int mb = blockIdx.x;            // 0..31 (rows mb*128..)
  const int nb = blockIdx.y;            // 0..15 (g cols nb*128..)
  const int lane = tid & 63;
  const int w = tid >> 6;
  const int wid = tid >> 6, wr = wid >> 1, wc = wid & 1;
  const short* at = zb + (size_t)mb * 16 * 8192;
  const short* b1t = w1b + (size_t)nb * 16 * 8192;
  const short* b2t = w1b + (size_t)(16 + nb) * 16 * 8192;
  f32x4 acc1[4][4], acc2[4][4];
  #pragma unroll
  for (int i = 0; i < 4; ++i)
    #pragma unroll
    for (int j = 0; j < 4; ++j) { acc1[i][j] = (f32x4)0.0f; acc2[i][j] = (f32x4)0.0f; }
  for (int kb = 0; kb < 16; ++kb) {
    #pragma unroll
    for (int i = 0; i < 4; ++i) {
      const int off = i * 2048 + w * 512;   // shorts
      gll16(at + (size_t)kb * 8192 + off + lane * 8, As + off, lane);
      gll16(b1t + (size_t)kb * 8192 + off + lane * 8, Bs1 + off, lane);
      gll16(b2t + (size_t)kb * 8192 + off + lane * 8, Bs2 + off, lane);
    }
    __syncthreads();   // drains gll16 (vmcnt 0) + orders vs prev reads
    #pragma unroll
    for (int ks = 0; ks < 2; ++ks) {
      short8 af[4], b1f[4], b2f[4];
      #pragma unroll
      for (int mf = 0; mf < 4; ++mf) {
        const int row = wr * 64 + mf * 16 + (lane & 15);
        const int c8 = ks * 4 + (lane >> 4);
        af[mf] = *(const short8*)&As[row * 64 + ((c8 ^ (row & 7)) << 3)];
      }
      #pragma unroll
      for (int nf = 0; nf < 4; ++nf) {
        const int row = wc * 64 + nf * 16 + (lane & 15);
        const int c8 = ks * 4 + (lane >> 4);
        const int off = row * 64 + ((c8 ^ (row & 7)) << 3);
        b1f[nf] = *(const short8*)&Bs1[off];
        b2f[nf] = *(const short8*)&Bs2[off];
      }
      #pragma unroll
      for (int mf = 0; mf < 4; ++mf)
        #pragma unroll
        for (int nf = 0; nf < 4; ++nf) {
          acc1[mf][nf] = __builtin_amdgcn_mfma_f32_16x16x32_bf16(af[mf], b1f[nf], acc1[mf][nf], 0, 0, 0);
          acc2[mf][nf] = __builtin_amdgcn_mfma_f32_16x16x32_bf16(af[mf], b2f[nf], acc2[mf][nf], 0, 0, 0);
        }
    }
    __syncthreads();
  }
  #pragma unroll
  for (int nf = 0; nf < 4; ++nf) {
    const int col = nb * 128 + wc * 64 + nf * 16 + (lane & 15);
    const float bx1 = b1[col], bx2 = b1[DFF + col];
    #pragma unroll
    for (int mf = 0; mf < 4; ++mf) {
      const int rloc = wr * 64 + mf * 16 + ((lane >> 4) << 2);   // 0..127
      #pragma unroll
      for (int rr = 0; rr < 4; ++rr) {
        const float x1 = acc1[mf][nf][rr] + bx1;
        const float x2 = acc2[mf][nf][rr] + bx2;
        const int r = rloc + rr;
        const size_t base = ((size_t)mb * 32 + (col >> 6)) * 8192;
        g[base + img_off(r, col & 63)] = (short)f2bf(x1 * gelu_exact(x2));
      }
    }
  }
}

// --------------- FF2 (bf16 MFMA, gll16) + bias + residual, in place ----------
__global__ __launch_bounds__(256) void ff2_gemm(
    const short* __restrict__ g, const short* __restrict__ w2b,
    const float* __restrict__ b2, float* __restrict__ out, int row0) {
  __shared__ short As[128 * 64];
  __shared__ short Bs[128 * 64];
  const int tid = threadIdx.x;
  const int mb = blockIdx.x;            // 0..31
  const int nb = blockIdx.y;            // 0..7
  const int lane = tid & 63;
  const int w = tid >> 6;
  const int wid = tid >> 6, wr = wid >> 1, wc = wid & 1;
  const short* at = g + (size_t)mb * 32 * 8192;
  const short* bt = w2b + (size_t)nb * 32 * 8192;
  f32x4 acc[4][4];
  #pragma unroll
  for (int i = 0; i < 4; ++i)
    #pragma unroll
    for (int j = 0; j < 4; ++j) acc[i][j] = (f32x4)0.0f;
  for (int kb = 0; kb < 32; ++kb) {
    #pragma unroll
    for (int i = 0; i < 4; ++i) {
      const int off = i * 2048 + w * 512;
      gll16(at + (size_t)kb * 8192 + off + lane * 8, As + off, lane);
      gll16(bt + (size_t)kb * 8192 + off + lane * 8, Bs + off, lane);
    }
    __syncthreads();
    #pragma unroll
    for (int ks = 0; ks < 2; ++ks) {
      short8 af[4], bf[4];
      #pragma unroll
      for (int mf = 0; mf < 4; ++mf) {
        const int row = wr * 64 + mf * 16 + (lane & 15);
        const int c8 = ks * 4 + (lane >> 4);
        af[mf] = *(const short8*)&As[row * 64 + ((c8 ^ (row & 7)) << 3)];
      }
      #pragma unroll
      for (int nf = 0; nf < 4; ++nf) {
        const int row = wc * 64 + nf * 16 + (lane & 15);
        const int c8 = ks * 4 + (lane >> 4);
        bf[nf] = *(const short8*)&Bs[row * 64 + ((c8 ^ (row & 7)) << 3)];
      }
      #pragma unroll
      for (int mf = 0; mf < 4; ++mf)
        #pragma unroll
        for (int nf = 0; nf < 4; ++nf)
          acc[mf][nf] = __builtin_amdgcn_mfma_f32_16x16x32_bf16(af[mf], bf[nf], acc[mf][nf], 0, 0, 0);
    }
    __syncthreads();
  }
  #pragma unroll
  for (int nf = 0; nf < 4; ++nf) {
    const int col = nb * 128 + wc * 64 + nf * 16 + (lane & 15);
    const float bias = b2[col];
    #pragma unroll
    for (int mf = 0; mf < 4; ++mf) {
      const int rbase = row0 + mb * 128 + wr * 64 + mf * 16 + ((lane >> 4) << 2);
      #pragma unroll
      for (int rr = 0; rr < 4; ++rr) {
        float* p = out + (size_t)(rbase + rr) * D_MODEL + col;
        *p = acc[mf][nf][rr] + bias + *p;
      }
    }
  }
}

// ------------------------------- launcher -----------------------------------
extern "C" void kernel_launch(void* const* d_in, const int* in_sizes, int n_in,
                              void* d_out, int out_size, void* d_ws, size_t ws_size,
                              hipStream_t stream) {
  const float* x    = (const float*)d_in[0];
  const float* ihw  = (const float*)d_in[1];
  const float* ihb  = (const float*)d_in[2];
  const float* hhw  = (const float*)d_in[3];
  const float* ln1w = (const float*)d_in[4];
  const float* ln1b = (const float*)d_in[5];
  const float* hnw  = (const float*)d_in[6];
  const float* hnb  = (const float*)d_in[7];
  const float* ln2w = (const float*)d_in[8];
  const float* ln2b = (const float*)d_in[9];
  const float* ffw1 = (const float*)d_in[10];
  const float* ffb1 = (const float*)d_in[11];
  const float* ffw2 = (const float*)d_in[12];
  const float* ffb2 = (const float*)d_in[13];

  float* ws    = (float*)d_ws;
  float* r0    = ws;                    // 8388608 floats: proj fp32; then g+zb
  float* state = ws + 8388608;          // 32768
  float* mu1   = ws + 8421376;
  float* rs1   = ws + 8437760;
  float* mu2   = ws + 8454144;
  float* rs2   = ws + 8470528;
  short* w1b   = (short*)(ws + 8486912);   // W1 tile images (8 MB)
  short* w2b   = (short*)(ws + 10584064);  // W2 tile images (4 MB)
  h2f*   hh2   = (h2f*)(ws + 11632640);    // 128 KB
  short* gb    = (short*)r0;               // g tile images, 4096x2048 (16 MB)
  short* zb    = (short*)(ws + 4194304);   // z tile images, 4096x1024 (8 MB)
  float* out   = (float*)d_out;

  cvt_w<<<dim3(4096 / 64, 1024 / 64), 256, 0, stream>>>(ffw1, w1b, 1024, 4096);
  cvt_w<<<dim3(1024 / 64, 2048 / 64), 256, 0, stream>>>(ffw2, w2b, 2048, 1024);
  cvt_hh<<<128, 256, 0, stream>>>(hhw, hh2);
  ln_stats_kernel<<<NROWS, 256, 0, stream>>>(x, mu1, rs1);
  for (int cidx = 0; cidx < SEQ / CHUNK_L; ++cidx) {
    const int l0 = cidx * CHUNK_L;
    proj_gemm<<<dim3(CHUNK_L * BATCH / 64, 512 / 128, NHEAD), 256, 0, stream>>>(
        x, mu1, rs1, ln1w, ln1b, ihw, ihb, r0, l0);
    scan_chunk<<<BATCH * NHEAD, 512, 0, stream>>>(r0, hh2, state, out, l0);
  }
  post_kernel<<<NROWS, 256, 0, stream>>>(out, x, hnw, hnb, mu2, rs2);
  for (int rc = 0; rc < NROWS / ROWCH; ++rc) {
    const int row0 = rc * ROWCH;
    cvt_z<<<ROWCH, 256, 0, stream>>>(out, mu2, rs2, ln2w, ln2b, zb, row0);
    ff1_gemm<<<dim3(ROWCH / 128, DFF / 128), 256, 0, stream>>>(zb, w1b, ffb1, gb);
    ff2_gemm<<<dim3(ROWCH / 128, D_MODEL / 128), 256, 0, stream>>>(
        gb, w2b, ffb2, out, row0);
  }
}

// Round 16
// 1952.892 us; speedup vs baseline: 1.0359x; 1.0359x over previous
//
#include <hip/hip_runtime.h>
#include <math.h>

// ---------------------------------------------------------------------------
// sLSTM block, round 16: proj goes bf16-MFMA (cvt_x tile images + gll16-staged
// proj_mfma with fused bias + bank-rotated store); scan gate math saves one
// exp via the max-trick. Everything else = r15.
// Workspace (floats): r0 32MB | state 128KB | mu/rs 256KB | w1b 8MB | w2b 4MB
//   | hh2 128KB | xb 4MB | ihwb 1MB   (~49.6 MB)
// ---------------------------------------------------------------------------

#define D_MODEL 1024
#define NHEAD   8
#define DPH     128
#define DFF     2048
#define BATCH   8
#define SEQ     2048
#define NROWS   (BATCH * SEQ)   // 16384
#define CHUNK_L 256             // scan steps per launch (8 launches)
#define TGRP    16              // scan steps per staged group (unrolled)
#define NGRP    (CHUNK_L / TGRP)
#define ROWCH   4096            // FFN rows per chunk (4 chunks)
#define LN_EPS  1e-5f

typedef __attribute__((ext_vector_type(8))) short short8;
typedef __attribute__((ext_vector_type(4))) short short4v;
typedef __attribute__((ext_vector_type(4))) float f32x4;
typedef __attribute__((ext_vector_type(2))) _Float16 h2f;
typedef __attribute__((ext_vector_type(8))) _Float16 h8f;
union H8U { h8f v; h2f p[4]; };

#if __has_builtin(__builtin_amdgcn_fdot2)
#define DOT2(a, b, c) __builtin_amdgcn_fdot2((a), (b), (c), false)
#else
__device__ __forceinline__ float DOT2(h2f a, h2f b, float c) {
  return c + (float)a.x * (float)b.x + (float)a.y * (float)b.y;
}
#endif

#if __has_builtin(__builtin_amdgcn_rcpf)
#define FRCP(x) __builtin_amdgcn_rcpf(x)
#else
#define FRCP(x) (1.0f / (x))
#endif

__device__ __forceinline__ float qxor1(float v) {
#if __has_builtin(__builtin_amdgcn_update_dpp)
  union { float f; int i; } u; u.f = v;
  u.i = __builtin_amdgcn_update_dpp(u.i, u.i, 0xB1, 0xf, 0xf, true);
  return u.f;
#else
  return __shfl_xor(v, 1, 64);
#endif
}
__device__ __forceinline__ float qxor2(float v) {
#if __has_builtin(__builtin_amdgcn_update_dpp)
  union { float f; int i; } u; u.f = v;
  u.i = __builtin_amdgcn_update_dpp(u.i, u.i, 0x4E, 0xf, 0xf, true);
  return u.f;
#else
  return __shfl_xor(v, 2, 64);
#endif
}

// async global->LDS, 16B per lane; lds_base must be WAVE-UNIFORM
__device__ __forceinline__ void gll16(const void* src, void* lds_base, int lane) {
#if __has_builtin(__builtin_amdgcn_global_load_lds)
  __builtin_amdgcn_global_load_lds(
      (const __attribute__((address_space(1))) unsigned int*)src,
      (__attribute__((address_space(3))) unsigned int*)lds_base, 16, 0, 0);
#else
  *(float4*)((char*)lds_base + lane * 16) = *(const float4*)src;
#endif
}

__device__ __forceinline__ float gelu_exact(float x) {
  return 0.5f * x * (1.0f + erff(x * 0.70710678118654752440f));
}

__device__ __forceinline__ unsigned short f2bf(float f) {
  union { float f; unsigned int u; } v; v.f = f;
  unsigned int r = v.u + 0x7fffu + ((v.u >> 16) & 1u);
  return (unsigned short)(r >> 16);
}

// tile-image offset for element (r, k) inside a [128][64] bf16 tile
__device__ __forceinline__ int img_off(int r, int k) {
  return r * 64 + ((((k >> 3) & 7) ^ (r & 7)) << 3) + (k & 7);
}

// sLSTM gate update: division-free + single-exp max-trick; returns raw h
__device__ __forceinline__ float gate_step(float iv, float fv, float zraw, float oraw,
                                           float& c, float& nrm, float& m) {
  const float zv = 1.0f - 2.0f * FRCP(__expf(2.0f * zraw) + 1.0f);
  const float ov = FRCP(1.0f + __expf(-oraw));
  const float lf = fminf(fv, 0.0f) - __logf(1.0f + __expf(-fabsf(fv)));
  const float ft = lf + m;
  const float mn = fmaxf(ft, iv);
  const float e  = __expf(fminf(ft, iv) - mn);   // exp(-|ft-iv|)
  const float is = (iv < ft) ? e : 1.0f;
  const float fs = (iv < ft) ? 1.0f : e;
  c = fs * c + is * zv;
  nrm = fs * nrm + is;
  m = mn;
  return ov * c * FRCP(nrm);
}

// --------------------- per-row LN stats (mu, rstd) --------------------------
__global__ __launch_bounds__(256) void ln_stats_kernel(
    const float* __restrict__ in, float* __restrict__ mu_out,
    float* __restrict__ rs_out) {
  const int row = blockIdx.x, tid = threadIdx.x;
  const float4 v = ((const float4*)(in + (size_t)row * D_MODEL))[tid];
  float s  = v.x + v.y + v.z + v.w;
  float s2 = v.x*v.x + v.y*v.y + v.z*v.z + v.w*v.w;
  #pragma unroll
  for (int m = 1; m < 64; m <<= 1) { s += __shfl_xor(s, m, 64); s2 += __shfl_xor(s2, m, 64); }
  __shared__ float sa[4], sb[4];
  if ((tid & 63) == 0) { sa[tid >> 6] = s; sb[tid >> 6] = s2; }
  __syncthreads();
  if (tid == 0) {
    const float S  = sa[0] + sa[1] + sa[2] + sa[3];
    const float S2 = sb[0] + sb[1] + sb[2] + sb[3];
    const float mu = S * (1.0f / D_MODEL);
    const float var = S2 * (1.0f / D_MODEL) - mu * mu;
    mu_out[row] = mu;
    rs_out[row] = rsqrtf(var + LN_EPS);
  }
}

// ---- weight convert: [K][N] f32 -> bf16 tile images [(n>>7)*(K/64)+(k>>6)] --
__global__ __launch_bounds__(256) void cvt_w(
    const float* __restrict__ src, short* __restrict__ dst, int K, int N) {
  __shared__ float tile[64][68];
  const int n0 = blockIdx.x * 64;
  const int k0 = blockIdx.y * 64;
  const int tid = threadIdx.x;
  #pragma unroll
  for (int i = 0; i < 16; ++i) {
    const int e = i * 256 + tid;
    const int kk = e >> 6, nn = e & 63;
    tile[kk][nn] = src[(size_t)(k0 + kk) * N + n0 + nn];
  }
  __syncthreads();
  const int ktiles = K >> 6;
  #pragma unroll
  for (int i = 0; i < 2; ++i) {
    const int e = i * 256 + tid;
    const int nn = e >> 3, kc = (e & 7) * 8;
    short8 s;
    #pragma unroll
    for (int j = 0; j < 8; ++j) s[j] = (short)f2bf(tile[kc + j][nn]);
    const int n = n0 + nn;
    const size_t base = ((size_t)(n >> 7) * ktiles + (k0 >> 6)) * 8192;
    *(short8*)(dst + base + img_off(n & 127, kc)) = s;
  }
}

// ---- hh_w [128][512] f32 -> packed f16 pairs hh2[k2][512] -------------------
__global__ __launch_bounds__(256) void cvt_hh(
    const float* __restrict__ hhw, h2f* __restrict__ hh2) {
  const int idx = blockIdx.x * 256 + threadIdx.x;
  const int k2 = idx >> 9, j = idx & 511;
  h2f v;
  v.x = (_Float16)hhw[(size_t)(2 * k2) * 512 + j];
  v.y = (_Float16)hhw[(size_t)(2 * k2 + 1) * 512 + j];
  hh2[idx] = v;
}

// ------ cvt_x: LN1(x) chunk rows as bf16 tile images -------------------------
// image id = ((rowm>>7)*8 + h)*2 + (khead>>6) ; rowm = lrel*8 + b
__global__ __launch_bounds__(256) void cvt_x(
    const float* __restrict__ x, const float* __restrict__ mu1,
    const float* __restrict__ rs1, const float* __restrict__ ln1w,
    const float* __restrict__ ln1b, short* __restrict__ xb, int l0) {
  const int rowm = blockIdx.x, tid = threadIdx.x;
  const int l = l0 + (rowm >> 3), b = rowm & 7;
  const int grow = b * SEQ + l;
  const float4 v = ((const float4*)(x + (size_t)grow * D_MODEL))[tid];
  const float mu = mu1[grow], rs = rs1[grow];
  const float4 w4 = ((const float4*)ln1w)[tid];
  const float4 b4 = ((const float4*)ln1b)[tid];
  short4v s;
  s[0] = (short)f2bf((v.x - mu) * rs * w4.x + b4.x);
  s[1] = (short)f2bf((v.y - mu) * rs * w4.y + b4.y);
  s[2] = (short)f2bf((v.z - mu) * rs * w4.z + b4.z);
  s[3] = (short)f2bf((v.w - mu) * rs * w4.w + b4.w);
  const int k = tid * 4;
  const int h = k >> 7, khead = k & 127;
  const size_t base = (((size_t)(rowm >> 7) * 8 + h) * 2 + (khead >> 6)) * 8192;
  *(short4v*)(xb + base + img_off(rowm & 127, khead & 63)) = s;
}

// ---------------- proj (bf16 MFMA, gll16) + bias, bank-rotated store ---------
__global__ __launch_bounds__(256) void proj_mfma(
    const short* __restrict__ xb, const short* __restrict__ ihwb,
    const float* __restrict__ ihb, float* __restrict__ proj) {
  __shared__ short As[128 * 64];
  __shared__ short Bs[128 * 64];
  const int tid = threadIdx.x;
  const int mb = blockIdx.x;            // 0..15
  const int qb = blockIdx.y;            // 0..3 (gate block)
  const int h  = blockIdx.z;            // 0..7
  const int lane = tid & 63;
  const int w = tid >> 6;
  const int wr = w >> 1, wc = w & 1;
  const short* at = xb + ((size_t)(mb * 8 + h) * 2) * 8192;
  const short* bt = ihwb + ((size_t)(h * 8 + qb * 2)) * 8192;
  f32x4 acc[4][4];
  #pragma unroll
  for (int i = 0; i < 4; ++i)
    #pragma unroll
    for (int j = 0; j < 4; ++j) acc[i][j] = (f32x4)0.0f;
  #pragma unroll
  for (int kb = 0; kb < 2; ++kb) {
    #pragma unroll
    for (int i = 0; i < 4; ++i) {
      const int off = i * 2048 + w * 512;
      gll16(at + (size_t)kb * 8192 + off + lane * 8, As + off, lane);
      gll16(bt + (size_t)kb * 8192 + off + lane * 8, Bs + off, lane);
    }
    __syncthreads();
    #pragma unroll
    for (int ks = 0; ks < 2; ++ks) {
      short8 af[4], bf[4];
      #pragma unroll
      for (int mf = 0; mf < 4; ++mf) {
        const int row = wr * 64 + mf * 16 + (lane & 15);
        const int c8 = ks * 4 + (lane >> 4);
        af[mf] = *(const short8*)&As[row * 64 + ((c8 ^ (row & 7)) << 3)];
      }
      #pragma unroll
      for (int nf = 0; nf < 4; ++nf) {
        const int row = wc * 64 + nf * 16 + (lane & 15);
        const int c8 = ks * 4 + (lane >> 4);
        bf[nf] = *(const short8*)&Bs[row * 64 + ((c8 ^ (row & 7)) << 3)];
      }
      #pragma unroll
      for (int mf = 0; mf < 4; ++mf)
        #pragma unroll
        for (int nf = 0; nf < 4; ++nf)
          acc[mf][nf] = __builtin_amdgcn_mfma_f32_16x16x32_bf16(af[mf], bf[nf], acc[mf][nf], 0, 0, 0);
    }
    __syncthreads();
  }
  #pragma unroll
  for (int nf = 0; nf < 4; ++nf) {
    const int col = wc * 64 + nf * 16 + (lane & 15);      // 0..127
    const float bias = ihb[h * 512 + qb * 128 + col];
    const int pos = qb * 128 + ((col + 8 * qb) & 127);    // bank-rotated
    #pragma unroll
    for (int mf = 0; mf < 4; ++mf) {
      const int rbase = mb * 128 + wr * 64 + mf * 16 + ((lane >> 4) << 2);
      #pragma unroll
      for (int rr = 0; rr < 4; ++rr)
        proj[((size_t)(rbase + rr) * NHEAD + h) * 512 + pos] = acc[mf][nf][rr] + bias;
    }
  }
}

// ------------------------------- sLSTM scan (r14/r15) -----------------------
__global__ __launch_bounds__(512, 1) void scan_chunk(
    const float* __restrict__ proj, const h2f* __restrict__ hh2,
    float* __restrict__ state, float* __restrict__ hout, int l0) {
  const int bh = blockIdx.x, b = bh >> 3, h = bh & 7;
  const int tid = threadIdx.x;
  const int l = tid & 63, w = tid >> 6;
  const int q = l & 3, p = l >> 2;
  const int ch = 16 * w + p;
  const int pvoff = q * 128 + ((ch + 8 * q) & 127);
  __shared__ __align__(16) _Float16 h16[2][128];
  __shared__ __align__(16) float pbuf[2][TGRP][512];
  __shared__ __align__(16) float hstage[2][TGRP][128];

  h2f w2[4][16];
  #pragma unroll
  for (int j = 0; j < 4; ++j)
    #pragma unroll
    for (int kk = 0; kk < 16; ++kk)
      w2[j][kk] = hh2[(size_t)(16 * q + kk) * 512 + j * 128 + ch];

  float c, nrm, m;
  if (l0 == 0) {
    c = 0.0f; nrm = 0.0f; m = -1e30f;
    if (q == 0) h16[0][ch] = (_Float16)0.0f;
  } else {
    c   = state[bh * 128 + ch];
    nrm = state[8192  + bh * 128 + ch];
    m   = state[16384 + bh * 128 + ch];
    if (q == 0) h16[0][ch] = (_Float16)state[24576 + bh * 128 + ch];
  }

  const float* pbase = proj + (size_t)bh * 512;

  #define STAGE(NB, GR)                                                        \
    {                                                                          \
      _Pragma("unroll")                                                        \
      for (int i = 0; i < 4; ++i) {                                            \
        const int hr = i * 8 + w;                                              \
        const float* src = pbase + (size_t)((GR) * TGRP + (hr >> 1)) * 32768   \
                           + (hr & 1) * 256 + l * 4;                           \
        float* dst = &pbuf[NB][0][0] + hr * 256;                               \
        gll16(src, dst, l);                                                    \
      }                                                                        \
    }

  STAGE(0, 0)
  asm volatile("s_waitcnt vmcnt(0)" ::: "memory");
  __syncthreads();

  float hv = 0.0f;
  for (int grp = 0; grp < NGRP; ++grp) {
    const int gb = grp & 1;
    if (grp + 1 < NGRP) STAGE(gb ^ 1, grp + 1)
    #pragma unroll
    for (int tl = 0; tl < TGRP; ++tl) {
      const int cur = tl & 1;
      float pa0 = 0.0f, pa1 = 0.0f, pa2 = 0.0f, pa3 = 0.0f;
      {
        const h8f* hp = (const h8f*)&h16[cur][q * 32];
        #pragma unroll
        for (int i = 0; i < 4; ++i) {
          H8U u; u.v = hp[i];
          #pragma unroll
          for (int e = 0; e < 4; ++e) {
            const int kk = i * 4 + e;
            pa0 = DOT2(u.p[e], w2[0][kk], pa0);
            pa1 = DOT2(u.p[e], w2[1][kk], pa1);
            pa2 = DOT2(u.p[e], w2[2][kk], pa2);
            pa3 = DOT2(u.p[e], w2[3][kk], pa3);
          }
        }
      }
      const float pv = pbuf[gb][tl][pvoff];
      pa0 += (q == 0) ? pv : 0.0f;
      pa1 += (q == 1) ? pv : 0.0f;
      pa2 += (q == 2) ? pv : 0.0f;
      pa3 += (q == 3) ? pv : 0.0f;
      pa0 += qxor1(pa0); pa1 += qxor1(pa1); pa2 += qxor1(pa2); pa3 += qxor1(pa3);
      pa0 += qxor2(pa0); pa1 += qxor2(pa1); pa2 += qxor2(pa2); pa3 += qxor2(pa3);
      hv = gate_step(pa0, pa1, pa2, pa3, c, nrm, m);
      if (q == 0) {
        h16[cur ^ 1][ch] = (_Float16)hv;
        hstage[gb][tl][ch] = hv;
      }
      __syncthreads();
    }
    {
      const int s = tid >> 5, c8 = (tid & 31) << 2;
      const float4 v0 = *(const float4*)&hstage[gb][s][c8];
      *(float4*)(hout + ((size_t)(b * SEQ + l0 + grp * TGRP + s)) * D_MODEL
                 + h * DPH + c8) = v0;
    }
  }

  if (q == 0) {
    state[bh * 128 + ch]          = c;
    state[8192  + bh * 128 + ch]  = nrm;
    state[16384 + bh * 128 + ch]  = m;
    state[24576 + bh * 128 + ch]  = hv;
  }
  #undef STAGE
}

// ---------- post: y = headLN(h) + x in place on d_out ; LN2 row stats -------
__global__ __launch_bounds__(256) void post_kernel(
    float* __restrict__ yio, const float* __restrict__ x,
    const float* __restrict__ hnw, const float* __restrict__ hnb,
    float* __restrict__ mu2, float* __restrict__ rs2) {
  const int row = blockIdx.x, tid = threadIdx.x;
  const float4 hv = ((const float4*)(yio + (size_t)row * D_MODEL))[tid];
  float s  = hv.x + hv.y + hv.z + hv.w;
  float s2 = hv.x*hv.x + hv.y*hv.y + hv.z*hv.z + hv.w*hv.w;
  #pragma unroll
  for (int mm = 1; mm < 32; mm <<= 1) {
    s  += __shfl_xor(s,  mm, 32);
    s2 += __shfl_xor(s2, mm, 32);
  }
  const float mu = s * (1.0f / DPH);
  const float var = s2 * (1.0f / DPH) - mu * mu;
  const float rstd = rsqrtf(var + LN_EPS);
  const int dq = tid & 31;
  const float4 w4 = ((const float4*)hnw)[dq];
  const float4 b4 = ((const float4*)hnb)[dq];
  const float4 xv = ((const float4*)(x + (size_t)row * D_MODEL))[tid];
  float4 yv;
  yv.x = (hv.x - mu) * rstd * w4.x + b4.x + xv.x;
  yv.y = (hv.y - mu) * rstd * w4.y + b4.y + xv.y;
  yv.z = (hv.z - mu) * rstd * w4.z + b4.z + xv.z;
  yv.w = (hv.w - mu) * rstd * w4.w + b4.w + xv.w;
  ((float4*)(yio + (size_t)row * D_MODEL))[tid] = yv;
  float t1 = yv.x + yv.y + yv.z + yv.w;
  float t2 = yv.x*yv.x + yv.y*yv.y + yv.z*yv.z + yv.w*yv.w;
  #pragma unroll
  for (int mm = 1; mm < 64; mm <<= 1) {
    t1 += __shfl_xor(t1, mm, 64);
    t2 += __shfl_xor(t2, mm, 64);
  }
  __shared__ float sa[4], sb[4];
  if ((tid & 63) == 0) { sa[tid >> 6] = t1; sb[tid >> 6] = t2; }
  __syncthreads();
  if (tid == 0) {
    const float S  = sa[0] + sa[1] + sa[2] + sa[3];
    const float S2 = sb[0] + sb[1] + sb[2] + sb[3];
    const float m2 = S * (1.0f / D_MODEL);
    const float v2 = S2 * (1.0f / D_MODEL) - m2 * m2;
    mu2[row] = m2;
    rs2[row] = rsqrtf(v2 + LN_EPS);
  }
}

// ------ cvt_z: z = LN2(y) as bf16 tile images (per ROWCH chunk) -------------
__global__ __launch_bounds__(256) void cvt_z(
    const float* __restrict__ y, const float* __restrict__ mu2,
    const float* __restrict__ rs2, const float* __restrict__ ln2w,
    const float* __restrict__ ln2b, short* __restrict__ zb, int row0) {
  const int lrow = blockIdx.x, tid = threadIdx.x;
  const int grow = row0 + lrow;
  const float4 v = ((const float4*)(y + (size_t)grow * D_MODEL))[tid];
  const float mu = mu2[grow], rs = rs2[grow];
  const float4 w4 = ((const float4*)ln2w)[tid];
  const float4 b4 = ((const float4*)ln2b)[tid];
  short4v s;
  s[0] = (short)f2bf((v.x - mu) * rs * w4.x + b4.x);
  s[1] = (short)f2bf((v.y - mu) * rs * w4.y + b4.y);
  s[2] = (short)f2bf((v.z - mu) * rs * w4.z + b4.z);
  s[3] = (short)f2bf((v.w - mu) * rs * w4.w + b4.w);
  const int k = tid * 4;
  const size_t base = ((size_t)(lrow >> 7) * 16 + (k >> 6)) * 8192;
  *(short4v*)(zb + base + img_off(lrow & 127, k & 63)) = s;
}

// ------------------------------ FF1 (bf16 MFMA, gll16) ----------------------
__global__ __launch_bounds__(256) void ff1_gemm(
    const short* __restrict__ zb, const short* __restrict__ w1b,
    const float* __restrict__ b1, short* __restrict__ g) {
  __shared__ short As[128 * 64];
  __shared__ short Bs1[128 * 64];
  __shared__ short Bs2[128 * 64];
  const int tid = threadIdx.x;
  const int mb = blockIdx.x;
  const int nb = blockIdx.y;
  const int lane = tid & 63;
  const int w = tid >> 6;
  const int wr = w >> 1, wc = w & 1;
  const short* at = zb + (size_t)mb * 16 * 8192;
  const short* b1t = w1b + (size_t)nb * 16 * 8192;
  const short* b2t = w1b + (size_t)(16 + nb) * 16 * 8192;
  f32x4 acc1[4][4], acc2[4][4];
  #pragma unroll
  for (int i = 0; i < 4; ++i)
    #pragma unroll
    for (int j = 0; j < 4; ++j) { acc1[i][j] = (f32x4)0.0f; acc2[i][j] = (f32x4)0.0f; }
  for (int kb = 0; kb < 16; ++kb) {
    #pragma unroll
    for (int i = 0; i < 4; ++i) {
      const int off = i * 2048 + w * 512;
      gll16(at + (size_t)kb * 8192 + off + lane * 8, As + off, lane);
      gll16(b1t + (size_t)kb * 8192 + off + lane * 8, Bs1 + off, lane);
      gll16(b2t + (size_t)kb * 8192 + off + lane * 8, Bs2 + off, lane);
    }
    __syncthreads();
    #pragma unroll
    for (int ks = 0; ks < 2; ++ks) {
      short8 af[4], b1f[4], b2f[4];
      #pragma unroll
      for (int mf = 0; mf < 4; ++mf) {
        const int row = wr * 64 + mf * 16 + (lane & 15);
        const int c8 = ks * 4 + (lane >> 4);
        af[mf] = *(const short8*)&As[row * 64 + ((c8 ^ (row & 7)) << 3)];
      }
      #pragma unroll
      for (int nf = 0; nf < 4; ++nf) {
        const int row = wc * 64 + nf * 16 + (lane & 15);
        const int c8 = ks * 4 + (lane >> 4);
        const int off = row * 64 + ((c8 ^ (row & 7)) << 3);
        b1f[nf] = *(const short8*)&Bs1[off];
        b2f[nf] = *(const short8*)&Bs2[off];
      }
      #pragma unroll
      for (int mf = 0; mf < 4; ++mf)
        #pragma unroll
        for (int nf = 0; nf < 4; ++nf) {
          acc1[mf][nf] = __builtin_amdgcn_mfma_f32_16x16x32_bf16(af[mf], b1f[nf], acc1[mf][nf], 0, 0, 0);
          acc2[mf][nf] = __builtin_amdgcn_mfma_f32_16x16x32_bf16(af[mf], b2f[nf], acc2[mf][nf], 0, 0, 0);
        }
    }
    __syncthreads();
  }
  #pragma unroll
  for (int nf = 0; nf < 4; ++nf) {
    const int col = nb * 128 + wc * 64 + nf * 16 + (lane & 15);
    const float bx1 = b1[col], bx2 = b1[DFF + col];
    #pragma unroll
    for (int mf = 0; mf < 4; ++mf) {
      const int rloc = wr * 64 + mf * 16 + ((lane >> 4) << 2);
      #pragma unroll
      for (int rr = 0; rr < 4; ++rr) {
        const float x1 = acc1[mf][nf][rr] + bx1;
        const float x2 = acc2[mf][nf][rr] + bx2;
        const int r = rloc + rr;
        const size_t base = ((size_t)mb * 32 + (col >> 6)) * 8192;
        g[base + img_off(r, col & 63)] = (short)f2bf(x1 * gelu_exact(x2));
      }
    }
  }
}

// --------------- FF2 (bf16 MFMA, gll16) + bias + residual, in place ----------
__global__ __launch_bounds__(256) void ff2_gemm(
    const short* __restrict__ g, const short* __restrict__ w2b,
    const float* __restrict__ b2, float* __restrict__ out, int row0) {
  __shared__ short As[128 * 64];
  __shared__ short Bs[128 * 64];
  const int tid = threadIdx.x;
  const int mb = blockIdx.x;
  const int nb = blockIdx.y;
  const int lane = tid & 63;
  const int w = tid >> 6;
  const int wr = w >> 1, wc = w & 1;
  const short* at = g + (size_t)mb * 32 * 8192;
  const short* bt = w2b + (size_t)nb * 32 * 8192;
  f32x4 acc[4][4];
  #pragma unroll
  for (int i = 0; i < 4; ++i)
    #pragma unroll
    for (int j = 0; j < 4; ++j) acc[i][j] = (f32x4)0.0f;
  for (int kb = 0; kb < 32; ++kb) {
    #pragma unroll
    for (int i = 0; i < 4; ++i) {
      const int off = i * 2048 + w * 512;
      gll16(at + (size_t)kb * 8192 + off + lane * 8, As + off, lane);
      gll16(bt + (size_t)kb * 8192 + off + lane * 8, Bs + off, lane);
    }
    __syncthreads();
    #pragma unroll
    for (int ks = 0; ks < 2; ++ks) {
      short8 af[4], bf[4];
      #pragma unroll
      for (int mf = 0; mf < 4; ++mf) {
        const int row = wr * 64 + mf * 16 + (lane & 15);
        const int c8 = ks * 4 + (lane >> 4);
        af[mf] = *(const short8*)&As[row * 64 + ((c8 ^ (row & 7)) << 3)];
      }
      #pragma unroll
      for (int nf = 0; nf < 4; ++nf) {
        const int row = wc * 64 + nf * 16 + (lane & 15);
        const int c8 = ks * 4 + (lane >> 4);
        bf[nf] = *(const short8*)&Bs[row * 64 + ((c8 ^ (row & 7)) << 3)];
      }
      #pragma unroll
      for (int mf = 0; mf < 4; ++mf)
        #pragma unroll
        for (int nf = 0; nf < 4; ++nf)
          acc[mf][nf] = __builtin_amdgcn_mfma_f32_16x16x32_bf16(af[mf], bf[nf], acc[mf][nf], 0, 0, 0);
    }
    __syncthreads();
  }
  #pragma unroll
  for (int nf = 0; nf < 4; ++nf) {
    const int col = nb * 128 + wc * 64 + nf * 16 + (lane & 15);
    const float bias = b2[col];
    #pragma unroll
    for (int mf = 0; mf < 4; ++mf) {
      const int rbase = row0 + mb * 128 + wr * 64 + mf * 16 + ((lane >> 4) << 2);
      #pragma unroll
      for (int rr = 0; rr < 4; ++rr) {
        float* p = out + (size_t)(rbase + rr) * D_MODEL + col;
        *p = acc[mf][nf][rr] + bias + *p;
      }
    }
  }
}

// ------------------------------- launcher -----------------------------------
extern "C" void kernel_launch(void* const* d_in, const int* in_sizes, int n_in,
                              void* d_out, int out_size, void* d_ws, size_t ws_size,
                              hipStream_t stream) {
  const float* x    = (const float*)d_in[0];
  const float* ihw  = (const float*)d_in[1];
  const float* ihb  = (const float*)d_in[2];
  const float* hhw  = (const float*)d_in[3];
  const float* ln1w = (const float*)d_in[4];
  const float* ln1b = (const float*)d_in[5];
  const float* hnw  = (const float*)d_in[6];
  const float* hnb  = (const float*)d_in[7];
  const float* ln2w = (const float*)d_in[8];
  const float* ln2b = (const float*)d_in[9];
  const float* ffw1 = (const float*)d_in[10];
  const float* ffb1 = (const float*)d_in[11];
  const float* ffw2 = (const float*)d_in[12];
  const float* ffb2 = (const float*)d_in[13];

  float* ws    = (float*)d_ws;
  float* r0    = ws;                       // proj fp32 chunk; later g+zb
  float* state = ws + 8388608;
  float* mu1   = ws + 8421376;
  float* rs1   = ws + 8437760;
  float* mu2   = ws + 8454144;
  float* rs2   = ws + 8470528;
  short* w1b   = (short*)(ws + 8486912);   // W1 tile images (8 MB)
  short* w2b   = (short*)(ws + 10584064);  // W2 tile images (4 MB)
  h2f*   hh2   = (h2f*)(ws + 11632640);    // 128 KB
  short* xb    = (short*)(ws + 11665408);  // x chunk tile images (4 MB)
  short* ihwb  = (short*)(ws + 12713984);  // ihw tile images (1 MB)
  short* gb    = (short*)r0;               // g tile images (16 MB)
  short* zb    = (short*)(ws + 4194304);   // z tile images (8 MB)
  float* out   = (float*)d_out;

  cvt_w<<<dim3(4096 / 64, 1024 / 64), 256, 0, stream>>>(ffw1, w1b, 1024, 4096);
  cvt_w<<<dim3(1024 / 64, 2048 / 64), 256, 0, stream>>>(ffw2, w2b, 2048, 1024);
  for (int h = 0; h < NHEAD; ++h)
    cvt_w<<<dim3(8, 2), 256, 0, stream>>>(ihw + (size_t)h * 65536,
                                          ihwb + (size_t)h * 8 * 8192, 128, 512);
  cvt_hh<<<128, 256, 0, stream>>>(hhw, hh2);
  ln_stats_kernel<<<NROWS, 256, 0, stream>>>(x, mu1, rs1);
  for (int cidx = 0; cidx < SEQ / CHUNK_L; ++cidx) {
    const int l0 = cidx * CHUNK_L;
    cvt_x<<<CHUNK_L * BATCH, 256, 0, stream>>>(x, mu1, rs1, ln1w, ln1b, xb, l0);
    proj_mfma<<<dim3(16, 4, NHEAD), 256, 0, stream>>>(xb, ihwb, ihb, r0);
    scan_chunk<<<BATCH * NHEAD, 512, 0, stream>>>(r0, hh2, state, out, l0);
  }
  post_kernel<<<NROWS, 256, 0, stream>>>(out, x, hnw, hnb, mu2, rs2);
  for (int rc = 0; rc < NROWS / ROWCH; ++rc) {
    const int row0 = rc * ROWCH;
    cvt_z<<<ROWCH, 256, 0, stream>>>(out, mu2, rs2, ln2w, ln2b, zb, row0);
    ff1_gemm<<<dim3(ROWCH / 128, DFF / 128), 256, 0, stream>>>(zb, w1b, ffb1, gb);
    ff2_gemm<<<dim3(ROWCH / 128, D_MODEL / 128), 256, 0, stream>>>(
        gb, w2b, ffb2, out, row0);
  }
}